// Round 1
// baseline (4208.553 us; speedup 1.0000x reference)
//
#include <hip/hip_runtime.h>

// Problem constants (fixed by the reference: N=50000, E=400000, D=128, H=256, L=5)
#define NNODES 50000
#define NEDGES 400000
#define DIM 128
#define HID 256
#define NLAYERS 5
#define BONDSZ 13
#define BN_EPS 1e-5f

// ---------------------------------------------------------------------------
// Edge pass: msg = relu(h[src] + bond0 + bond1 + bond2); atomicAdd into agg[dst]
// 8 edges per 256-thread block-iteration; 32 threads (float4 each) per edge.
// Bond table (13x128 = 6.6KB) staged in LDS once per block.
// ---------------------------------------------------------------------------
__global__ __launch_bounds__(256) void edge_kernel(
    const float* __restrict__ h, const int* __restrict__ src,
    const int* __restrict__ dst, const int* __restrict__ eattr,
    const float* __restrict__ bond, float* __restrict__ agg)
{
    __shared__ float T[BONDSZ * DIM];
    for (int i = threadIdx.x; i < BONDSZ * DIM; i += 256) T[i] = bond[i];
    __syncthreads();

    const int lane = threadIdx.x & 31;
    const int f = lane * 4;
    const int eloc = threadIdx.x >> 5;

    for (int e = blockIdx.x * 8 + eloc; e < NEDGES; e += gridDim.x * 8) {
        int s  = src[e];
        int d  = dst[e];
        int a0 = eattr[e * 3 + 0];
        int a1 = eattr[e * 3 + 1] + 5;
        int a2 = eattr[e * 3 + 2] + 11;
        float4 hv = *(const float4*)&h[(size_t)s * DIM + f];
        float4 t0 = *(const float4*)&T[a0 * DIM + f];
        float4 t1 = *(const float4*)&T[a1 * DIM + f];
        float4 t2 = *(const float4*)&T[a2 * DIM + f];
        float m0 = fmaxf(hv.x + t0.x + t1.x + t2.x, 0.0f);
        float m1 = fmaxf(hv.y + t0.y + t1.y + t2.y, 0.0f);
        float m2 = fmaxf(hv.z + t0.z + t1.z + t2.z, 0.0f);
        float m3 = fmaxf(hv.w + t0.w + t1.w + t2.w, 0.0f);
        float* ap = &agg[(size_t)d * DIM + f];
        atomicAdd(ap + 0, m0);
        atomicAdd(ap + 1, m1);
        atomicAdd(ap + 2, m2);
        atomicAdd(ap + 3, m3);
    }
}

// ---------------------------------------------------------------------------
// z = (1 + eps[l]) * h + agg   (elementwise, float4)
// ---------------------------------------------------------------------------
__global__ __launch_bounds__(256) void gin_combine(
    const float* __restrict__ h, const float* __restrict__ agg,
    const float* __restrict__ epsv, int lidx, float* __restrict__ z, int n4)
{
    int i = blockIdx.x * 256 + threadIdx.x;
    if (i >= n4) return;
    float e = 1.0f + epsv[lidx];
    float4 hv = *(const float4*)&h[(size_t)i * 4];
    float4 av = *(const float4*)&agg[(size_t)i * 4];
    float4 zv;
    zv.x = e * hv.x + av.x;
    zv.y = e * hv.y + av.y;
    zv.z = e * hv.z + av.z;
    zv.w = e * hv.w + av.w;
    *(float4*)&z[(size_t)i * 4] = zv;
}

// ---------------------------------------------------------------------------
// GEMM: C[M,Ncols] = op(A)[M,K] @ B[K,Ncols] + bias, where
//   op(A) = transformA ? relu(sA[k]*A + tA[k]) : A   (BN+ReLU fused on A-load)
// Fused epilogue: per-column sum and sum-of-squares of C (valid rows only),
// block-reduced in LDS then one atomicAdd per column per block.
// Tiling: BM=64, BN=64, BK=16; 256 threads; 4x4 per-thread microtile.
// ---------------------------------------------------------------------------
__global__ __launch_bounds__(256) void gemm_bn(
    const float* __restrict__ A, const float* __restrict__ B,
    const float* __restrict__ bias,
    const float* __restrict__ sA, const float* __restrict__ tA, int transformA,
    float* __restrict__ C, float* __restrict__ colsum, float* __restrict__ colsumsq,
    int M, int K, int Ncols)
{
    __shared__ float As[16][64];
    __shared__ float Bs[16][64];
    __shared__ float red1[16][64];
    __shared__ float red2[16][64];

    const int tid = threadIdx.x;
    const int tr = tid >> 4;        // 0..15 (row group)
    const int tc = tid & 15;        // 0..15 (col group)
    const int m0 = blockIdx.y * 64;
    const int n0 = blockIdx.x * 64;
    const int arow = tid >> 2;          // 0..63
    const int acol = (tid & 3) * 4;     // 0..12
    const int brow = tid >> 4;          // 0..15
    const int bcol = (tid & 15) * 4;    // 0..60

    float acc[4][4] = {};

    for (int k0 = 0; k0 < K; k0 += 16) {
        // ---- load A tile (64x16), optionally transformed
        float4 av = make_float4(0.f, 0.f, 0.f, 0.f);
        int r = m0 + arow;
        if (r < M) av = *(const float4*)&A[(size_t)r * K + k0 + acol];
        if (transformA) {
            float4 s = *(const float4*)&sA[k0 + acol];
            float4 t = *(const float4*)&tA[k0 + acol];
            av.x = fmaxf(av.x * s.x + t.x, 0.f);
            av.y = fmaxf(av.y * s.y + t.y, 0.f);
            av.z = fmaxf(av.z * s.z + t.z, 0.f);
            av.w = fmaxf(av.w * s.w + t.w, 0.f);
        }
        As[acol + 0][arow] = av.x;
        As[acol + 1][arow] = av.y;
        As[acol + 2][arow] = av.z;
        As[acol + 3][arow] = av.w;
        // ---- load B tile (16x64)
        float4 bv = *(const float4*)&B[(size_t)(k0 + brow) * Ncols + n0 + bcol];
        *(float4*)&Bs[brow][bcol] = bv;
        __syncthreads();

        #pragma unroll
        for (int kk = 0; kk < 16; kk++) {
            float4 a4 = *(const float4*)&As[kk][tr * 4];
            float4 b4 = *(const float4*)&Bs[kk][tc * 4];
            float a[4] = {a4.x, a4.y, a4.z, a4.w};
            float b[4] = {b4.x, b4.y, b4.z, b4.w};
            #pragma unroll
            for (int i = 0; i < 4; i++)
                #pragma unroll
                for (int j = 0; j < 4; j++)
                    acc[i][j] += a[i] * b[j];
        }
        __syncthreads();
    }

    // ---- epilogue: bias, store, per-column partial sums
    const int row0 = m0 + tr * 4;
    const int col0 = n0 + tc * 4;
    float4 bv = *(const float4*)&bias[col0];
    float bb[4] = {bv.x, bv.y, bv.z, bv.w};
    float csum[4] = {0.f, 0.f, 0.f, 0.f};
    float csq[4] = {0.f, 0.f, 0.f, 0.f};
    #pragma unroll
    for (int i = 0; i < 4; i++) {
        int r = row0 + i;
        if (r < M) {
            float c[4];
            #pragma unroll
            for (int j = 0; j < 4; j++) {
                c[j] = acc[i][j] + bb[j];
                csum[j] += c[j];
                csq[j] += c[j] * c[j];
            }
            float4 cv = make_float4(c[0], c[1], c[2], c[3]);
            *(float4*)&C[(size_t)r * Ncols + col0] = cv;
        }
    }
    #pragma unroll
    for (int j = 0; j < 4; j++) {
        red1[tr][tc * 4 + j] = csum[j];
        red2[tr][tc * 4 + j] = csq[j];
    }
    __syncthreads();
    if (tid < 64) {
        float s = 0.f, q = 0.f;
        #pragma unroll
        for (int t = 0; t < 16; t++) {
            s += red1[t][tid];
            q += red2[t][tid];
        }
        atomicAdd(&colsum[n0 + tid], s);
        atomicAdd(&colsumsq[n0 + tid], q);
    }
}

// ---------------------------------------------------------------------------
// BN finalize: scale = gamma * rsqrt(var + eps), shift = beta - mu*scale
// ---------------------------------------------------------------------------
__global__ __launch_bounds__(256) void bn_finalize(
    const float* __restrict__ colsum, const float* __restrict__ colsumsq,
    const float* __restrict__ gamma, const float* __restrict__ beta,
    float* __restrict__ scale, float* __restrict__ shift, int H, float invN)
{
    int j = blockIdx.x * blockDim.x + threadIdx.x;
    if (j >= H) return;
    float mu = colsum[j] * invN;
    float var = colsumsq[j] * invN - mu * mu;
    float s = gamma[j] * rsqrtf(var + BN_EPS);
    scale[j] = s;
    shift[j] = beta[j] - mu * s;
}

// ---------------------------------------------------------------------------
// BN apply (+ optional inter-layer ReLU): out = act(scale[c]*y + shift[c])
// ---------------------------------------------------------------------------
__global__ __launch_bounds__(256) void bn_apply(
    const float* __restrict__ y, const float* __restrict__ scale,
    const float* __restrict__ shift, float* __restrict__ out, int n4, int relu)
{
    int i = blockIdx.x * 256 + threadIdx.x;
    if (i >= n4) return;
    int c = (i & 31) * 4;   // D=128 -> 32 float4 per row
    float4 v = *(const float4*)&y[(size_t)i * 4];
    float4 s = *(const float4*)&scale[c];
    float4 t = *(const float4*)&shift[c];
    v.x = v.x * s.x + t.x;
    v.y = v.y * s.y + t.y;
    v.z = v.z * s.z + t.z;
    v.w = v.w * s.w + t.w;
    if (relu) {
        v.x = fmaxf(v.x, 0.f);
        v.y = fmaxf(v.y, 0.f);
        v.z = fmaxf(v.z, 0.f);
        v.w = fmaxf(v.w, 0.f);
    }
    *(float4*)&out[(size_t)i * 4] = v;
}

extern "C" void kernel_launch(void* const* d_in, const int* in_sizes, int n_in,
                              void* d_out, int out_size, void* d_ws, size_t ws_size,
                              hipStream_t stream)
{
    const float* x    = (const float*)d_in[0];
    const int*   ei   = (const int*)d_in[1];
    const int*   ea   = (const int*)d_in[2];
    const float* W1   = (const float*)d_in[3];
    const float* b1   = (const float*)d_in[4];
    const float* g1   = (const float*)d_in[5];
    const float* bb1  = (const float*)d_in[6];
    const float* W2   = (const float*)d_in[7];
    const float* b2   = (const float*)d_in[8];
    const float* epsv = (const float*)d_in[9];
    const float* bond = (const float*)d_in[10];
    const float* g2   = (const float*)d_in[11];
    const float* bb2  = (const float*)d_in[12];
    float* out = (float*)d_out;

    const int* src = ei;
    const int* dstp = ei + NEDGES;

    // workspace layout (floats)
    float* ws   = (float*)d_ws;
    float* h    = ws;                       // 6.4M
    float* agg  = h + (size_t)NNODES * DIM; // 6.4M
    float* z    = agg + (size_t)NNODES * DIM;
    float* y1   = z + (size_t)NNODES * DIM;     // 12.8M
    float* y2   = y1 + (size_t)NNODES * HID;    // 6.4M
    float* stats = y2 + (size_t)NNODES * DIM;
    float* cs1 = stats;          // 256
    float* cq1 = cs1 + HID;      // 256
    float* cs2 = cq1 + HID;      // 128
    float* cq2 = cs2 + DIM;      // 128  -> sums region = 768 floats
    float* sc1 = stats + 768;
    float* sh1 = sc1 + HID;
    float* sc2 = sh1 + HID;
    float* sh2 = sc2 + DIM;

    hipMemcpyAsync(h, x, (size_t)NNODES * DIM * sizeof(float),
                   hipMemcpyDeviceToDevice, stream);

    const int n4 = NNODES * DIM / 4;        // 1,600,000
    const dim3 gemm1_grid(HID / 64, (NNODES + 63) / 64);   // (4, 782)
    const dim3 gemm2_grid(DIM / 64, (NNODES + 63) / 64);   // (2, 782)

    for (int l = 0; l < NLAYERS; l++) {
        hipMemsetAsync(agg, 0, (size_t)NNODES * DIM * sizeof(float), stream);
        hipMemsetAsync(stats, 0, 768 * sizeof(float), stream);

        edge_kernel<<<2000, 256, 0, stream>>>(
            h, src, dstp, ea, bond + (size_t)l * BONDSZ * DIM, agg);

        gin_combine<<<(n4 + 255) / 256, 256, 0, stream>>>(h, agg, epsv, l, z, n4);

        gemm_bn<<<gemm1_grid, 256, 0, stream>>>(
            z, W1 + (size_t)l * DIM * HID, b1 + (size_t)l * HID,
            nullptr, nullptr, 0, y1, cs1, cq1, NNODES, DIM, HID);

        bn_finalize<<<1, HID, 0, stream>>>(
            cs1, cq1, g1 + (size_t)l * HID, bb1 + (size_t)l * HID,
            sc1, sh1, HID, 1.0f / NNODES);

        gemm_bn<<<gemm2_grid, 256, 0, stream>>>(
            y1, W2 + (size_t)l * HID * DIM, b2 + (size_t)l * DIM,
            sc1, sh1, 1, y2, cs2, cq2, NNODES, HID, DIM);

        bn_finalize<<<1, DIM, 0, stream>>>(
            cs2, cq2, g2 + (size_t)l * DIM, bb2 + (size_t)l * DIM,
            sc2, sh2, DIM, 1.0f / NNODES);

        bn_apply<<<(n4 + 255) / 256, 256, 0, stream>>>(
            y2, sc2, sh2, (l == NLAYERS - 1) ? out : h, n4, (l < NLAYERS - 1) ? 1 : 0);
    }
}

// Round 2
// 1124.318 us; speedup vs baseline: 3.7432x; 3.7432x over previous
//
#include <hip/hip_runtime.h>

// Problem constants (fixed by the reference: N=50000, E=400000, D=128, H=256, L=5)
#define NNODES 50000
#define NEDGES 400000
#define DIM 128
#define HID 256
#define NLAYERS 5
#define BONDSZ 13
#define BN_EPS 1e-5f
#define NCHUNK 49   // ceil(50000/1024)

// ===========================================================================
// CSR build (once per call — edge topology is layer-invariant)
// ===========================================================================
__global__ __launch_bounds__(256) void hist_kernel(
    const int* __restrict__ dst, int* __restrict__ deg)
{
    int e = blockIdx.x * 256 + threadIdx.x;
    if (e < NEDGES) atomicAdd(&deg[dst[e]], 1);
}

__global__ __launch_bounds__(256) void scan_sum(
    const int* __restrict__ deg, int* __restrict__ partial)
{
    __shared__ int red[256];
    int base = blockIdx.x * 1024;
    int s = 0;
    for (int i = threadIdx.x; i < 1024; i += 256) {
        int idx = base + i;
        if (idx < NNODES) s += deg[idx];
    }
    red[threadIdx.x] = s;
    __syncthreads();
    for (int off = 128; off > 0; off >>= 1) {
        if (threadIdx.x < off) red[threadIdx.x] += red[threadIdx.x + off];
        __syncthreads();
    }
    if (threadIdx.x == 0) partial[blockIdx.x] = red[0];
}

__global__ void scan_part(int* __restrict__ partial, int n, int* __restrict__ rowptr_last)
{
    if (threadIdx.x == 0) {
        int acc = 0;
        for (int i = 0; i < n; i++) { int v = partial[i]; partial[i] = acc; acc += v; }
        rowptr_last[0] = acc;  // row_ptr[NNODES] = total edges
    }
}

__global__ __launch_bounds__(256) void scan_write(
    const int* __restrict__ deg, const int* __restrict__ partial,
    int* __restrict__ row_ptr)
{
    __shared__ int red[256];
    int base = blockIdx.x * 1024;
    int t = threadIdx.x;
    int v[4];
    int s = 0;
    #pragma unroll
    for (int j = 0; j < 4; j++) {
        int idx = base + t * 4 + j;
        v[j] = (idx < NNODES) ? deg[idx] : 0;
        s += v[j];
    }
    red[t] = s;
    __syncthreads();
    // inclusive Hillis-Steele scan over 256 thread sums
    for (int off = 1; off < 256; off <<= 1) {
        int x = (t >= off) ? red[t - off] : 0;
        __syncthreads();
        red[t] += x;
        __syncthreads();
    }
    int ex = red[t] - s + partial[blockIdx.x];   // exclusive prefix for this thread
    #pragma unroll
    for (int j = 0; j < 4; j++) {
        int idx = base + t * 4 + j;
        if (idx < NNODES) row_ptr[idx] = ex;
        ex += v[j];
    }
}

__global__ __launch_bounds__(256) void scatter_kernel(
    const int* __restrict__ src, const int* __restrict__ dst,
    const int* __restrict__ eattr, const int* __restrict__ row_ptr,
    int* __restrict__ cursor, int* __restrict__ esrc, int* __restrict__ ebond)
{
    int e = blockIdx.x * 256 + threadIdx.x;
    if (e >= NEDGES) return;
    int d = dst[e];
    int pos = row_ptr[d] + atomicAdd(&cursor[d], 1);
    esrc[pos] = src[e];
    int a0 = eattr[e * 3 + 0];
    int a1 = eattr[e * 3 + 1];
    int a2 = eattr[e * 3 + 2];
    ebond[pos] = a0 | ((5 + a1) << 4) | ((11 + a2) << 8);   // 3 packed table rows
}

// ===========================================================================
// Aggregation + GIN combine, CSR form: one wave (64 lanes, float2/lane) per
// node. acc = sum_{e in in(n)} relu(h[src[e]] + T[i0]+T[i1]+T[i2]);
// z[n] = (1+eps)*h[n] + acc.  Zero atomics; bond table (6.6 KB) in LDS.
// ===========================================================================
__global__ __launch_bounds__(256) void agg_combine(
    const float* __restrict__ h, const int* __restrict__ row_ptr,
    const int* __restrict__ esrc, const int* __restrict__ ebond,
    const float* __restrict__ bond, const float* __restrict__ epsv, int lidx,
    float* __restrict__ z)
{
    __shared__ float T[BONDSZ * DIM];
    for (int i = threadIdx.x; i < BONDSZ * DIM; i += 256) T[i] = bond[i];
    __syncthreads();

    const int wave = threadIdx.x >> 6;
    const int lane = threadIdx.x & 63;
    const int node = blockIdx.x * 4 + wave;
    if (node >= NNODES) return;
    const int f = lane * 2;

    float2 acc = make_float2(0.f, 0.f);
    const int s = row_ptr[node];
    const int e2 = row_ptr[node + 1];
    for (int i = s; i < e2; i++) {
        int sn = esrc[i];
        int pk = ebond[i];
        float2 hv = *(const float2*)&h[(size_t)sn * DIM + f];
        float2 t0 = *(const float2*)&T[(pk & 15) * DIM + f];
        float2 t1 = *(const float2*)&T[((pk >> 4) & 15) * DIM + f];
        float2 t2 = *(const float2*)&T[((pk >> 8) & 15) * DIM + f];
        acc.x += fmaxf(hv.x + t0.x + t1.x + t2.x, 0.f);
        acc.y += fmaxf(hv.y + t0.y + t1.y + t2.y, 0.f);
    }
    float ep = 1.0f + epsv[lidx];
    float2 hv = *(const float2*)&h[(size_t)node * DIM + f];
    float2 zv;
    zv.x = ep * hv.x + acc.x;
    zv.y = ep * hv.y + acc.y;
    *(float2*)&z[(size_t)node * DIM + f] = zv;
}

// ---------------------------------------------------------------------------
// GEMM: C[M,Ncols] = op(A)[M,K] @ B[K,Ncols] + bias, where
//   op(A) = transformA ? relu(sA[k]*A + tA[k]) : A   (BN+ReLU fused on A-load)
// Fused epilogue: per-column sum / sum-of-squares (block LDS reduce + atomic).
// Tiling: BM=64, BN=64, BK=16; 256 threads; 4x4 per-thread microtile.
// ---------------------------------------------------------------------------
__global__ __launch_bounds__(256) void gemm_bn(
    const float* __restrict__ A, const float* __restrict__ B,
    const float* __restrict__ bias,
    const float* __restrict__ sA, const float* __restrict__ tA, int transformA,
    float* __restrict__ C, float* __restrict__ colsum, float* __restrict__ colsumsq,
    int M, int K, int Ncols)
{
    __shared__ float As[16][64];
    __shared__ float Bs[16][64];
    __shared__ float red1[16][64];
    __shared__ float red2[16][64];

    const int tid = threadIdx.x;
    const int tr = tid >> 4;
    const int tc = tid & 15;
    const int m0 = blockIdx.y * 64;
    const int n0 = blockIdx.x * 64;
    const int arow = tid >> 2;
    const int acol = (tid & 3) * 4;
    const int brow = tid >> 4;
    const int bcol = (tid & 15) * 4;

    float acc[4][4] = {};

    for (int k0 = 0; k0 < K; k0 += 16) {
        float4 av = make_float4(0.f, 0.f, 0.f, 0.f);
        int r = m0 + arow;
        if (r < M) av = *(const float4*)&A[(size_t)r * K + k0 + acol];
        if (transformA) {
            float4 s = *(const float4*)&sA[k0 + acol];
            float4 t = *(const float4*)&tA[k0 + acol];
            av.x = fmaxf(av.x * s.x + t.x, 0.f);
            av.y = fmaxf(av.y * s.y + t.y, 0.f);
            av.z = fmaxf(av.z * s.z + t.z, 0.f);
            av.w = fmaxf(av.w * s.w + t.w, 0.f);
        }
        As[acol + 0][arow] = av.x;
        As[acol + 1][arow] = av.y;
        As[acol + 2][arow] = av.z;
        As[acol + 3][arow] = av.w;
        float4 bv = *(const float4*)&B[(size_t)(k0 + brow) * Ncols + n0 + bcol];
        *(float4*)&Bs[brow][bcol] = bv;
        __syncthreads();

        #pragma unroll
        for (int kk = 0; kk < 16; kk++) {
            float4 a4 = *(const float4*)&As[kk][tr * 4];
            float4 b4 = *(const float4*)&Bs[kk][tc * 4];
            float a[4] = {a4.x, a4.y, a4.z, a4.w};
            float b[4] = {b4.x, b4.y, b4.z, b4.w};
            #pragma unroll
            for (int i = 0; i < 4; i++)
                #pragma unroll
                for (int j = 0; j < 4; j++)
                    acc[i][j] += a[i] * b[j];
        }
        __syncthreads();
    }

    const int row0 = m0 + tr * 4;
    const int col0 = n0 + tc * 4;
    float4 bv = *(const float4*)&bias[col0];
    float bb[4] = {bv.x, bv.y, bv.z, bv.w};
    float csum[4] = {0.f, 0.f, 0.f, 0.f};
    float csq[4] = {0.f, 0.f, 0.f, 0.f};
    #pragma unroll
    for (int i = 0; i < 4; i++) {
        int r = row0 + i;
        if (r < M) {
            float c[4];
            #pragma unroll
            for (int j = 0; j < 4; j++) {
                c[j] = acc[i][j] + bb[j];
                csum[j] += c[j];
                csq[j] += c[j] * c[j];
            }
            float4 cv = make_float4(c[0], c[1], c[2], c[3]);
            *(float4*)&C[(size_t)r * Ncols + col0] = cv;
        }
    }
    #pragma unroll
    for (int j = 0; j < 4; j++) {
        red1[tr][tc * 4 + j] = csum[j];
        red2[tr][tc * 4 + j] = csq[j];
    }
    __syncthreads();
    if (tid < 64) {
        float s = 0.f, q = 0.f;
        #pragma unroll
        for (int t = 0; t < 16; t++) {
            s += red1[t][tid];
            q += red2[t][tid];
        }
        atomicAdd(&colsum[n0 + tid], s);
        atomicAdd(&colsumsq[n0 + tid], q);
    }
}

__global__ __launch_bounds__(256) void bn_finalize(
    const float* __restrict__ colsum, const float* __restrict__ colsumsq,
    const float* __restrict__ gamma, const float* __restrict__ beta,
    float* __restrict__ scale, float* __restrict__ shift, int H, float invN)
{
    int j = blockIdx.x * blockDim.x + threadIdx.x;
    if (j >= H) return;
    float mu = colsum[j] * invN;
    float var = colsumsq[j] * invN - mu * mu;
    float s = gamma[j] * rsqrtf(var + BN_EPS);
    scale[j] = s;
    shift[j] = beta[j] - mu * s;
}

__global__ __launch_bounds__(256) void bn_apply(
    const float* __restrict__ y, const float* __restrict__ scale,
    const float* __restrict__ shift, float* __restrict__ out, int n4, int relu)
{
    int i = blockIdx.x * 256 + threadIdx.x;
    if (i >= n4) return;
    int c = (i & 31) * 4;   // D=128 -> 32 float4 per row
    float4 v = *(const float4*)&y[(size_t)i * 4];
    float4 s = *(const float4*)&scale[c];
    float4 t = *(const float4*)&shift[c];
    v.x = v.x * s.x + t.x;
    v.y = v.y * s.y + t.y;
    v.z = v.z * s.z + t.z;
    v.w = v.w * s.w + t.w;
    if (relu) {
        v.x = fmaxf(v.x, 0.f);
        v.y = fmaxf(v.y, 0.f);
        v.z = fmaxf(v.z, 0.f);
        v.w = fmaxf(v.w, 0.f);
    }
    *(float4*)&out[(size_t)i * 4] = v;
}

extern "C" void kernel_launch(void* const* d_in, const int* in_sizes, int n_in,
                              void* d_out, int out_size, void* d_ws, size_t ws_size,
                              hipStream_t stream)
{
    const float* x    = (const float*)d_in[0];
    const int*   ei   = (const int*)d_in[1];
    const int*   ea   = (const int*)d_in[2];
    const float* W1   = (const float*)d_in[3];
    const float* b1   = (const float*)d_in[4];
    const float* g1   = (const float*)d_in[5];
    const float* bb1  = (const float*)d_in[6];
    const float* W2   = (const float*)d_in[7];
    const float* b2   = (const float*)d_in[8];
    const float* epsv = (const float*)d_in[9];
    const float* bond = (const float*)d_in[10];
    const float* g2   = (const float*)d_in[11];
    const float* bb2  = (const float*)d_in[12];
    float* out = (float*)d_out;

    const int* src = ei;
    const int* dstp = ei + NEDGES;

    // workspace layout
    float* ws = (float*)d_ws;
    float* h  = ws;                              // N*D = 6.4M floats
    float* z  = h + (size_t)NNODES * DIM;        // 6.4M
    float* y1 = z + (size_t)NNODES * DIM;        // N*H = 12.8M
    float* y2 = y1 + (size_t)NNODES * HID;       // 6.4M
    float* stats = y2 + (size_t)NNODES * DIM;
    float* cs1 = stats;          // 256
    float* cq1 = cs1 + HID;      // 256
    float* cs2 = cq1 + HID;      // 128
    float* cq2 = cs2 + DIM;      // 128  -> zeroed region = 768 floats
    float* sc1 = stats + 768;
    float* sh1 = sc1 + HID;
    float* sc2 = sh1 + HID;
    float* sh2 = sc2 + DIM;
    int* iws     = (int*)(sh2 + DIM);
    int* deg     = iws;                  // 50000
    int* cursor  = deg + NNODES;         // 50000   (deg+cursor zeroed together)
    int* row_ptr = cursor + NNODES;      // 50001
    int* partial = row_ptr + NNODES + 1; // 64
    int* esrc    = partial + 64;         // 400000
    int* ebond   = esrc + NEDGES;        // 400000

    hipMemcpyAsync(h, x, (size_t)NNODES * DIM * sizeof(float),
                   hipMemcpyDeviceToDevice, stream);

    // ---- build CSR (dst-sorted edge list), once
    hipMemsetAsync(deg, 0, 2 * NNODES * sizeof(int), stream);
    hist_kernel<<<(NEDGES + 255) / 256, 256, 0, stream>>>(dstp, deg);
    scan_sum<<<NCHUNK, 256, 0, stream>>>(deg, partial);
    scan_part<<<1, 64, 0, stream>>>(partial, NCHUNK, row_ptr + NNODES);
    scan_write<<<NCHUNK, 256, 0, stream>>>(deg, partial, row_ptr);
    scatter_kernel<<<(NEDGES + 255) / 256, 256, 0, stream>>>(
        src, dstp, ea, row_ptr, cursor, esrc, ebond);

    const int n4 = NNODES * DIM / 4;    // 1,600,000
    const dim3 gemm1_grid(HID / 64, (NNODES + 63) / 64);   // (4, 782)
    const dim3 gemm2_grid(DIM / 64, (NNODES + 63) / 64);   // (2, 782)

    for (int l = 0; l < NLAYERS; l++) {
        hipMemsetAsync(stats, 0, 768 * sizeof(float), stream);

        agg_combine<<<(NNODES + 3) / 4, 256, 0, stream>>>(
            h, row_ptr, esrc, ebond, bond + (size_t)l * BONDSZ * DIM, epsv, l, z);

        gemm_bn<<<gemm1_grid, 256, 0, stream>>>(
            z, W1 + (size_t)l * DIM * HID, b1 + (size_t)l * HID,
            nullptr, nullptr, 0, y1, cs1, cq1, NNODES, DIM, HID);

        bn_finalize<<<1, HID, 0, stream>>>(
            cs1, cq1, g1 + (size_t)l * HID, bb1 + (size_t)l * HID,
            sc1, sh1, HID, 1.0f / NNODES);

        gemm_bn<<<gemm2_grid, 256, 0, stream>>>(
            y1, W2 + (size_t)l * HID * DIM, b2 + (size_t)l * DIM,
            sc1, sh1, 1, y2, cs2, cq2, NNODES, HID, DIM);

        bn_finalize<<<1, DIM, 0, stream>>>(
            cs2, cq2, g2 + (size_t)l * DIM, bb2 + (size_t)l * DIM,
            sc2, sh2, DIM, 1.0f / NNODES);

        bn_apply<<<(n4 + 255) / 256, 256, 0, stream>>>(
            y2, sc2, sh2, (l == NLAYERS - 1) ? out : h, n4, (l < NLAYERS - 1) ? 1 : 0);
    }
}

// Round 3
// 900.474 us; speedup vs baseline: 4.6737x; 1.2486x over previous
//
#include <hip/hip_runtime.h>
#include <hip/hip_bf16.h>

// Problem constants (fixed by the reference: N=50000, E=400000, D=128, H=256, L=5)
#define NNODES 50000
#define NEDGES 400000
#define DIM 128
#define HID 256
#define NLAYERS 5
#define BONDSZ 13
#define BN_EPS 1e-5f
#define NCHUNK 49   // ceil(50000/1024)

typedef __bf16 bf16x8 __attribute__((ext_vector_type(8)));
typedef float f32x4 __attribute__((ext_vector_type(4)));

// ===========================================================================
// CSR build (once per call — edge topology is layer-invariant)
// ===========================================================================
__global__ __launch_bounds__(256) void hist_kernel(
    const int* __restrict__ dst, int* __restrict__ deg)
{
    int e = blockIdx.x * 256 + threadIdx.x;
    if (e < NEDGES) atomicAdd(&deg[dst[e]], 1);
}

__global__ __launch_bounds__(256) void scan_sum(
    const int* __restrict__ deg, int* __restrict__ partial)
{
    __shared__ int red[256];
    int base = blockIdx.x * 1024;
    int s = 0;
    for (int i = threadIdx.x; i < 1024; i += 256) {
        int idx = base + i;
        if (idx < NNODES) s += deg[idx];
    }
    red[threadIdx.x] = s;
    __syncthreads();
    for (int off = 128; off > 0; off >>= 1) {
        if (threadIdx.x < off) red[threadIdx.x] += red[threadIdx.x + off];
        __syncthreads();
    }
    if (threadIdx.x == 0) partial[blockIdx.x] = red[0];
}

__global__ void scan_part(int* __restrict__ partial, int n, int* __restrict__ rowptr_last)
{
    if (threadIdx.x == 0) {
        int acc = 0;
        for (int i = 0; i < n; i++) { int v = partial[i]; partial[i] = acc; acc += v; }
        rowptr_last[0] = acc;
    }
}

__global__ __launch_bounds__(256) void scan_write(
    const int* __restrict__ deg, const int* __restrict__ partial,
    int* __restrict__ row_ptr)
{
    __shared__ int red[256];
    int base = blockIdx.x * 1024;
    int t = threadIdx.x;
    int v[4];
    int s = 0;
    #pragma unroll
    for (int j = 0; j < 4; j++) {
        int idx = base + t * 4 + j;
        v[j] = (idx < NNODES) ? deg[idx] : 0;
        s += v[j];
    }
    red[t] = s;
    __syncthreads();
    for (int off = 1; off < 256; off <<= 1) {
        int x = (t >= off) ? red[t - off] : 0;
        __syncthreads();
        red[t] += x;
        __syncthreads();
    }
    int ex = red[t] - s + partial[blockIdx.x];
    #pragma unroll
    for (int j = 0; j < 4; j++) {
        int idx = base + t * 4 + j;
        if (idx < NNODES) row_ptr[idx] = ex;
        ex += v[j];
    }
}

__global__ __launch_bounds__(256) void scatter_kernel(
    const int* __restrict__ src, const int* __restrict__ dst,
    const int* __restrict__ eattr, const int* __restrict__ row_ptr,
    int* __restrict__ cursor, int* __restrict__ esrc, int* __restrict__ ebond)
{
    int e = blockIdx.x * 256 + threadIdx.x;
    if (e >= NEDGES) return;
    int d = dst[e];
    int pos = row_ptr[d] + atomicAdd(&cursor[d], 1);
    esrc[pos] = src[e];
    int a0 = eattr[e * 3 + 0];
    int a1 = eattr[e * 3 + 1];
    int a2 = eattr[e * 3 + 2];
    ebond[pos] = a0 | ((5 + a1) << 4) | ((11 + a2) << 8);
}

// ===========================================================================
// Aggregation + GIN combine (CSR, zero atomics), edge loop unrolled x4 so 4
// gather rows are in flight (breaks the dependent-load chain).
// One wave per node, float2 per lane.
// ===========================================================================
__global__ __launch_bounds__(256) void agg_combine(
    const float* __restrict__ h, const int* __restrict__ row_ptr,
    const int* __restrict__ esrc, const int* __restrict__ ebond,
    const float* __restrict__ bond, const float* __restrict__ epsv, int lidx,
    float* __restrict__ z)
{
    __shared__ float T[BONDSZ * DIM];
    for (int i = threadIdx.x; i < BONDSZ * DIM; i += 256) T[i] = bond[i];
    __syncthreads();

    const int wave = threadIdx.x >> 6;
    const int lane = threadIdx.x & 63;
    const int node = blockIdx.x * 4 + wave;
    if (node >= NNODES) return;
    const int f = lane * 2;

    float accx = 0.f, accy = 0.f;
    const int s = row_ptr[node];
    const int e2 = row_ptr[node + 1];
    int i = s;
    for (; i + 3 < e2; i += 4) {
        int sn0 = esrc[i], sn1 = esrc[i + 1], sn2 = esrc[i + 2], sn3 = esrc[i + 3];
        int pk0 = ebond[i], pk1 = ebond[i + 1], pk2 = ebond[i + 2], pk3 = ebond[i + 3];
        float2 h0 = *(const float2*)&h[(size_t)sn0 * DIM + f];
        float2 h1 = *(const float2*)&h[(size_t)sn1 * DIM + f];
        float2 h2 = *(const float2*)&h[(size_t)sn2 * DIM + f];
        float2 h3 = *(const float2*)&h[(size_t)sn3 * DIM + f];
        {
            float2 a = *(const float2*)&T[(pk0 & 15) * DIM + f];
            float2 b = *(const float2*)&T[((pk0 >> 4) & 15) * DIM + f];
            float2 c = *(const float2*)&T[((pk0 >> 8) & 15) * DIM + f];
            accx += fmaxf(h0.x + a.x + b.x + c.x, 0.f);
            accy += fmaxf(h0.y + a.y + b.y + c.y, 0.f);
        }
        {
            float2 a = *(const float2*)&T[(pk1 & 15) * DIM + f];
            float2 b = *(const float2*)&T[((pk1 >> 4) & 15) * DIM + f];
            float2 c = *(const float2*)&T[((pk1 >> 8) & 15) * DIM + f];
            accx += fmaxf(h1.x + a.x + b.x + c.x, 0.f);
            accy += fmaxf(h1.y + a.y + b.y + c.y, 0.f);
        }
        {
            float2 a = *(const float2*)&T[(pk2 & 15) * DIM + f];
            float2 b = *(const float2*)&T[((pk2 >> 4) & 15) * DIM + f];
            float2 c = *(const float2*)&T[((pk2 >> 8) & 15) * DIM + f];
            accx += fmaxf(h2.x + a.x + b.x + c.x, 0.f);
            accy += fmaxf(h2.y + a.y + b.y + c.y, 0.f);
        }
        {
            float2 a = *(const float2*)&T[(pk3 & 15) * DIM + f];
            float2 b = *(const float2*)&T[((pk3 >> 4) & 15) * DIM + f];
            float2 c = *(const float2*)&T[((pk3 >> 8) & 15) * DIM + f];
            accx += fmaxf(h3.x + a.x + b.x + c.x, 0.f);
            accy += fmaxf(h3.y + a.y + b.y + c.y, 0.f);
        }
    }
    for (; i < e2; i++) {
        int sn = esrc[i];
        int pk = ebond[i];
        float2 hv = *(const float2*)&h[(size_t)sn * DIM + f];
        float2 a = *(const float2*)&T[(pk & 15) * DIM + f];
        float2 b = *(const float2*)&T[((pk >> 4) & 15) * DIM + f];
        float2 c = *(const float2*)&T[((pk >> 8) & 15) * DIM + f];
        accx += fmaxf(hv.x + a.x + b.x + c.x, 0.f);
        accy += fmaxf(hv.y + a.y + b.y + c.y, 0.f);
    }
    float ep = 1.0f + epsv[lidx];
    float2 hv = *(const float2*)&h[(size_t)node * DIM + f];
    float2 zv;
    zv.x = ep * hv.x + accx;
    zv.y = ep * hv.y + accy;
    *(float2*)&z[(size_t)node * DIM + f] = zv;
}

// ===========================================================================
// Split-precision bf16 MFMA GEMM (fp32-accurate: aH*bH + aL*bH + aH*bL).
// C[M,NCOLS] = op(A)[M,K] @ B[K,NCOLS] + bias
//   op(A) = TRANSFORM ? relu(sA[k]*A + tA[k]) : A    (BN+ReLU fused on A-load)
// Fused epilogue: per-column sum / sum-sq via LDS atomics + 1 global atomic.
// Block tile 128x128, 4 waves (2x2 of 64x64), 16x16x32 bf16 MFMA, BK=32.
// ===========================================================================
#define BK 32
#define LDK 40   // padded LDS k-stride (80B: 16B-aligned, 2-way bank max on frag reads)

template<int K, int NCOLS, int TRANSFORM>
__global__ __launch_bounds__(256) void gemm_mfma(
    const float* __restrict__ A, const float* __restrict__ B,
    const float* __restrict__ bias,
    const float* __restrict__ sA, const float* __restrict__ tA,
    float* __restrict__ C, float* __restrict__ colsum, float* __restrict__ colsumsq,
    int M)
{
    __shared__ __bf16 AsH[128 * LDK];
    __shared__ __bf16 AsL[128 * LDK];
    __shared__ __bf16 BsH[128 * LDK];
    __shared__ __bf16 BsL[128 * LDK];
    __shared__ float redS[128];
    __shared__ float redQ[128];

    const int tid = threadIdx.x;
    const int lane = tid & 63;
    const int wv = tid >> 6;
    const int wave_m = (wv >> 1) * 64;
    const int wave_n = (wv & 1) * 64;
    const int rowL = lane & 15;
    const int kQ = lane >> 4;          // 0..3

    const int m0 = blockIdx.y * 128;
    const int n0 = blockIdx.x * 128;

    if (tid < 128) { redS[tid] = 0.f; redQ[tid] = 0.f; }

    f32x4 acc[4][4] = {};

    // staging indices
    const int arow = tid >> 1;             // 0..127
    const int akoff = (tid & 1) * 16;      // 0 or 16
    const int bcol = tid & 127;            // 0..127
    const int bkoff = (tid >> 7) * 16;     // 0 or 16

    for (int kt = 0; kt < K; kt += BK) {
        // ---- stage A tile (128 x 32) with hi/lo bf16 split
        {
            float f[16];
            int grow = m0 + arow;
            if (grow < M) {
                const float* ap = &A[(size_t)grow * K + kt + akoff];
                #pragma unroll
                for (int q = 0; q < 4; q++) {
                    float4 v = *(const float4*)&ap[q * 4];
                    f[q * 4 + 0] = v.x; f[q * 4 + 1] = v.y;
                    f[q * 4 + 2] = v.z; f[q * 4 + 3] = v.w;
                }
            } else {
                #pragma unroll
                for (int q = 0; q < 16; q++) f[q] = 0.f;
            }
            if (TRANSFORM) {
                #pragma unroll
                for (int q = 0; q < 16; q++) {
                    float sv = sA[kt + akoff + q];
                    float tv = tA[kt + akoff + q];
                    f[q] = fmaxf(f[q] * sv + tv, 0.f);
                }
            }
            #pragma unroll
            for (int q = 0; q < 16; q++) {
                __bf16 hi = (__bf16)f[q];
                __bf16 lo = (__bf16)(f[q] - (float)hi);
                AsH[arow * LDK + akoff + q] = hi;
                AsL[arow * LDK + akoff + q] = lo;
            }
        }
        // ---- stage B tile (32 x 128), transposed to [col][k], hi/lo split
        {
            const float* bp = &B[(size_t)(kt + bkoff) * NCOLS + n0 + bcol];
            #pragma unroll
            for (int q = 0; q < 16; q++) {
                float fv = bp[(size_t)q * NCOLS];
                __bf16 hi = (__bf16)fv;
                __bf16 lo = (__bf16)(fv - (float)hi);
                BsH[bcol * LDK + bkoff + q] = hi;
                BsL[bcol * LDK + bkoff + q] = lo;
            }
        }
        __syncthreads();

        bf16x8 aH[4], aL[4], bH[4], bL[4];
        #pragma unroll
        for (int i = 0; i < 4; i++) {
            int off = (wave_m + i * 16 + rowL) * LDK + kQ * 8;
            aH[i] = *(const bf16x8*)&AsH[off];
            aL[i] = *(const bf16x8*)&AsL[off];
        }
        #pragma unroll
        for (int j = 0; j < 4; j++) {
            int off = (wave_n + j * 16 + rowL) * LDK + kQ * 8;
            bH[j] = *(const bf16x8*)&BsH[off];
            bL[j] = *(const bf16x8*)&BsL[off];
        }
        #pragma unroll
        for (int i = 0; i < 4; i++)
            #pragma unroll
            for (int j = 0; j < 4; j++) {
                acc[i][j] = __builtin_amdgcn_mfma_f32_16x16x32_bf16(aH[i], bH[j], acc[i][j], 0, 0, 0);
                acc[i][j] = __builtin_amdgcn_mfma_f32_16x16x32_bf16(aL[i], bH[j], acc[i][j], 0, 0, 0);
                acc[i][j] = __builtin_amdgcn_mfma_f32_16x16x32_bf16(aH[i], bL[j], acc[i][j], 0, 0, 0);
            }
        __syncthreads();
    }

    // ---- epilogue: bias, store C, per-column stats
    #pragma unroll
    for (int j = 0; j < 4; j++) {
        int col = wave_n + j * 16 + rowL;          // 0..127 (within block tile)
        float bb = bias[n0 + col];
        float sj = 0.f, qj = 0.f;
        #pragma unroll
        for (int i = 0; i < 4; i++) {
            int rbase = m0 + wave_m + i * 16 + kQ * 4;
            #pragma unroll
            for (int r = 0; r < 4; r++) {
                int rr = rbase + r;
                if (rr < M) {
                    float v = acc[i][j][r] + bb;
                    C[(size_t)rr * NCOLS + n0 + col] = v;
                    sj += v;
                    qj += v * v;
                }
            }
        }
        atomicAdd(&redS[col], sj);
        atomicAdd(&redQ[col], qj);
    }
    __syncthreads();
    if (tid < 128) {
        atomicAdd(&colsum[n0 + tid], redS[tid]);
        atomicAdd(&colsumsq[n0 + tid], redQ[tid]);
    }
}

__global__ __launch_bounds__(256) void bn_finalize(
    const float* __restrict__ colsum, const float* __restrict__ colsumsq,
    const float* __restrict__ gamma, const float* __restrict__ beta,
    float* __restrict__ scale, float* __restrict__ shift, int H, float invN)
{
    int j = blockIdx.x * blockDim.x + threadIdx.x;
    if (j >= H) return;
    float mu = colsum[j] * invN;
    float var = colsumsq[j] * invN - mu * mu;
    float s = gamma[j] * rsqrtf(var + BN_EPS);
    scale[j] = s;
    shift[j] = beta[j] - mu * s;
}

__global__ __launch_bounds__(256) void bn_apply(
    const float* __restrict__ y, const float* __restrict__ scale,
    const float* __restrict__ shift, float* __restrict__ out, int n4, int relu)
{
    int i = blockIdx.x * 256 + threadIdx.x;
    if (i >= n4) return;
    int c = (i & 31) * 4;   // D=128 -> 32 float4 per row
    float4 v = *(const float4*)&y[(size_t)i * 4];
    float4 s = *(const float4*)&scale[c];
    float4 t = *(const float4*)&shift[c];
    v.x = v.x * s.x + t.x;
    v.y = v.y * s.y + t.y;
    v.z = v.z * s.z + t.z;
    v.w = v.w * s.w + t.w;
    if (relu) {
        v.x = fmaxf(v.x, 0.f);
        v.y = fmaxf(v.y, 0.f);
        v.z = fmaxf(v.z, 0.f);
        v.w = fmaxf(v.w, 0.f);
    }
    *(float4*)&out[(size_t)i * 4] = v;
}

extern "C" void kernel_launch(void* const* d_in, const int* in_sizes, int n_in,
                              void* d_out, int out_size, void* d_ws, size_t ws_size,
                              hipStream_t stream)
{
    const float* x    = (const float*)d_in[0];
    const int*   ei   = (const int*)d_in[1];
    const int*   ea   = (const int*)d_in[2];
    const float* W1   = (const float*)d_in[3];
    const float* b1   = (const float*)d_in[4];
    const float* g1   = (const float*)d_in[5];
    const float* bb1  = (const float*)d_in[6];
    const float* W2   = (const float*)d_in[7];
    const float* b2   = (const float*)d_in[8];
    const float* epsv = (const float*)d_in[9];
    const float* bond = (const float*)d_in[10];
    const float* g2   = (const float*)d_in[11];
    const float* bb2  = (const float*)d_in[12];
    float* out = (float*)d_out;

    const int* src = ei;
    const int* dstp = ei + NEDGES;

    // workspace layout
    float* ws = (float*)d_ws;
    float* h  = ws;                              // N*D
    float* z  = h + (size_t)NNODES * DIM;
    float* y1 = z + (size_t)NNODES * DIM;        // N*H
    float* y2 = y1 + (size_t)NNODES * HID;
    float* stats = y2 + (size_t)NNODES * DIM;
    float* cs1 = stats;          // 256
    float* cq1 = cs1 + HID;      // 256
    float* cs2 = cq1 + HID;      // 128
    float* cq2 = cs2 + DIM;      // 128  -> zeroed region = 768 floats
    float* sc1 = stats + 768;
    float* sh1 = sc1 + HID;
    float* sc2 = sh1 + HID;
    float* sh2 = sc2 + DIM;
    int* iws     = (int*)(sh2 + DIM);
    int* deg     = iws;                  // 50000
    int* cursor  = deg + NNODES;         // 50000
    int* row_ptr = cursor + NNODES;      // 50001
    int* partial = row_ptr + NNODES + 1; // 64
    int* esrc    = partial + 64;         // 400000
    int* ebond   = esrc + NEDGES;        // 400000

    hipMemcpyAsync(h, x, (size_t)NNODES * DIM * sizeof(float),
                   hipMemcpyDeviceToDevice, stream);

    // ---- build CSR (dst-sorted edge list), once
    hipMemsetAsync(deg, 0, 2 * NNODES * sizeof(int), stream);
    hist_kernel<<<(NEDGES + 255) / 256, 256, 0, stream>>>(dstp, deg);
    scan_sum<<<NCHUNK, 256, 0, stream>>>(deg, partial);
    scan_part<<<1, 64, 0, stream>>>(partial, NCHUNK, row_ptr + NNODES);
    scan_write<<<NCHUNK, 256, 0, stream>>>(deg, partial, row_ptr);
    scatter_kernel<<<(NEDGES + 255) / 256, 256, 0, stream>>>(
        src, dstp, ea, row_ptr, cursor, esrc, ebond);

    const int n4 = NNODES * DIM / 4;
    const int mtiles = (NNODES + 127) / 128;     // 391
    const dim3 g1grid(HID / 128, mtiles);        // (2, 391)
    const dim3 g2grid(DIM / 128, mtiles);        // (1, 391)

    for (int l = 0; l < NLAYERS; l++) {
        hipMemsetAsync(stats, 0, 768 * sizeof(float), stream);

        agg_combine<<<(NNODES + 3) / 4, 256, 0, stream>>>(
            h, row_ptr, esrc, ebond, bond + (size_t)l * BONDSZ * DIM, epsv, l, z);

        gemm_mfma<DIM, HID, 0><<<g1grid, 256, 0, stream>>>(
            z, W1 + (size_t)l * DIM * HID, b1 + (size_t)l * HID,
            nullptr, nullptr, y1, cs1, cq1, NNODES);

        bn_finalize<<<1, HID, 0, stream>>>(
            cs1, cq1, g1 + (size_t)l * HID, bb1 + (size_t)l * HID,
            sc1, sh1, HID, 1.0f / NNODES);

        gemm_mfma<HID, DIM, 1><<<g2grid, 256, 0, stream>>>(
            y1, W2 + (size_t)l * HID * DIM, b2 + (size_t)l * DIM,
            sc1, sh1, y2, cs2, cq2, NNODES);

        bn_finalize<<<1, DIM, 0, stream>>>(
            cs2, cq2, g2 + (size_t)l * DIM, bb2 + (size_t)l * DIM,
            sc2, sh2, DIM, 1.0f / NNODES);

        bn_apply<<<(n4 + 255) / 256, 256, 0, stream>>>(
            y2, sc2, sh2, (l == NLAYERS - 1) ? out : h, n4, (l < NLAYERS - 1) ? 1 : 0);
    }
}